// Round 11
// baseline (396.092 us; speedup 1.0000x reference)
//
#include <hip/hip_runtime.h>
#include <hip/hip_fp16.h>
#include <math.h>

// Problem constants: N=100000, E=400000, G=64, IN=8, H=4, C=64, HD=256.
// R28: gemm K=256 REVERTED from R27 direct-global (87us: MFMA stalled on
// ~200cy L2-hit vmcnt; LDS round-trip IS the latency hider) back to the
// proven R24b pipeline (DMA staging -> LDS K-loop -> full-line tbuf
// stores), restructured as M=32 / 4-wave (256thr) blocks: same per-thread
// work and regs (acc[2][8]=64 AGPR; <=64 VGPR via 2A+4B live frags), but
// 4 blocks/CU instead of 2 (finer granularity at the 128-reg/16-wave cap)
// -> 4 independent barrier groups overlap stage/compute/epilogue. 3
// barriers, no idle-wave phases (single-pass 32x516 tbuf, every wave owns
// its own 8-ct column range). B re-reads double but stay L2-resident.
// Alias safe: block touches only its own 32 A-rows. Tripwires: FETCH
// ~29MB, WRITE 100MB, dur<57.5 else revert.
// Rest = R24b exact (gemm64 8-wave dual w/ fused encoder; gat diet:
// padded edata, cndmask gathers, exp2; 2048-block pool; CSR build).

#define HD 256
#define NHEAD 4
#define CH 64

typedef _Float16 half8 __attribute__((ext_vector_type(8)));
typedef _Float16 h2 __attribute__((ext_vector_type(2)));
typedef __attribute__((ext_vector_type(4))) float f32x4;

__device__ __forceinline__ h2 pack_h2(float a, float b) {
#if __has_builtin(__builtin_amdgcn_cvt_pkrtz)
    return __builtin_bit_cast(h2, __builtin_amdgcn_cvt_pkrtz(a, b));
#else
    return h2{(_Float16)a, (_Float16)b};
#endif
}

__device__ __forceinline__ float fast_exp2(float x) {
#if __has_builtin(__builtin_amdgcn_exp2f)
    return __builtin_amdgcn_exp2f(x);
#else
    return exp2f(x);
#endif
}

__device__ __forceinline__ float dot2f(h2 a, h2 b, float c) {
#if __has_builtin(__builtin_amdgcn_fdot2)
    typedef __fp16 fp16v2 __attribute__((ext_vector_type(2)));
    return __builtin_amdgcn_fdot2(__builtin_bit_cast(fp16v2, a),
                                  __builtin_bit_cast(fp16v2, b), c, false);
#else
    return c + (float)a.x * (float)b.x + (float)a.y * (float)b.y;
#endif
}

// ---------------------------------------------------------------------------
// prep_w helper: Wl,Wr [K,256] fp32 -> fp16 B-frag layout (single region).
// Lane holds B[k=(l>>4)*8+j][n=l&15] of tile (ks,ct); ct<16->Wl, else Wr.
// ---------------------------------------------------------------------------
__device__ __forceinline__ void prep_one(const float* Wl, const float* Wr,
                                         ushort* frag, int K, int t) {
    int l = t & 63;
    int ct = (t >> 6) & 31;
    int ks = t >> 11;
    int n = l & 15, q = l >> 4;
    const float* W = (ct < 16) ? Wl : Wr;
    int col = (ct & 15) * 16 + n;
    ushort* phi = frag + (size_t)t * 8;
#pragma unroll
    for (int j = 0; j < 8; ++j) {
        int k = ks * 32 + q * 8 + j;
        float wv = W[(size_t)k * 256 + col];
        phi[j] = __half_as_ushort(__float2half(wv));
    }
}

__global__ void setup_kernel(int* __restrict__ zbase, int nzero,
                             const float* __restrict__ Wl1, const float* __restrict__ Wr1,
                             ushort* __restrict__ f1,
                             const float* __restrict__ Wl2, const float* __restrict__ Wr2,
                             ushort* __restrict__ f2) {
    int i = blockIdx.x * 256 + threadIdx.x;
    if (i < nzero) {
        zbase[i] = 0;
    } else {
        int gt = i - nzero;
        if (gt < 64 * 64) prep_one(Wl1, Wr1, f1, 64, gt);
        else if (gt < 64 * 64 + 256 * 64) prep_one(Wl2, Wr2, f2, 256, gt - 64 * 64);
    }
}

// ---------------------------------------------------------------------------
// CSR build: degree histogram -> scan (2 kernels) -> scatter (packed int2).
// ---------------------------------------------------------------------------
__global__ void deg_kernel(const int* __restrict__ dst, int* __restrict__ cnt, int E) {
    int e = blockIdx.x * 256 + threadIdx.x;
    if (e < E) atomicAdd(&cnt[dst[e]], 1);
}

__global__ void scan_block(const int* __restrict__ cnt, int* __restrict__ off,
                           int* __restrict__ bsum, int N) {
    __shared__ int s[256];
    int i = blockIdx.x * 256 + threadIdx.x;
    int v = (i < N) ? cnt[i] : 0;
    s[threadIdx.x] = v;
    __syncthreads();
    for (int d = 1; d < 256; d <<= 1) {
        int t = 0;
        if (threadIdx.x >= d) t = s[threadIdx.x - d];
        __syncthreads();
        s[threadIdx.x] += t;
        __syncthreads();
    }
    if (i < N) off[i + 1] = s[threadIdx.x];
    if (threadIdx.x == 255) bsum[blockIdx.x] = s[255];
    if (blockIdx.x == 0 && threadIdx.x == 0) off[0] = 0;
}

__global__ void scan_add2(int* __restrict__ off, const int* __restrict__ bsum, int N) {
    __shared__ int red[4];
    int b = blockIdx.x;
    int s = 0;
    for (int i = threadIdx.x; i < b; i += 256) s += bsum[i];
    for (int o = 32; o > 0; o >>= 1) s += __shfl_xor(s, o);
    if ((threadIdx.x & 63) == 0) red[threadIdx.x >> 6] = s;
    __syncthreads();
    int prefix = red[0] + red[1] + red[2] + red[3];
    int i = b * 256 + threadIdx.x;
    if (i < N) off[i + 1] += prefix;
}

// edata.x = src*512 (byte offset of row in fp16 [N,256] buffer; fits 31 bits)
__global__ void scatter_kernel(const int* __restrict__ dst, const int* __restrict__ src,
                               const float* __restrict__ eattr, const int* __restrict__ off,
                               int* __restrict__ cur, int2* __restrict__ edata, int E) {
    int e = blockIdx.x * 256 + threadIdx.x;
    if (e < E) {
        int d = dst[e];
        int p = atomicAdd(&cur[d], 1);
        edata[off[d] + p] = make_int2(src[e] << 9, __float_as_int(eattr[e]));
    }
}

// ---------------------------------------------------------------------------
// FP16 MFMA dual GEMM (R24b form) — used for K=64 FUSE_ENC only.
// 512 thr (8 waves), 64 rows, LDS staging w/ fused encoder, ds_read K-loop,
// two-pass tbuf 64x260 epilogue with uint4 full-line row stores.
// ---------------------------------------------------------------------------
template <int K, bool FUSE_ENC>
__global__ __launch_bounds__(512, 4) void gemm_mfma(
    const void* Av, const float* __restrict__ Wenc, const float* __restrict__ benc,
    const ushort* __restrict__ Bfrag,
    const float* __restrict__ bl, const float* __restrict__ br,
    ushort* __restrict__ outL, ushort* outR, int N) {
    constexpr int KS = K / 32;
    constexpr int FRAG_SHORTS = KS * 4 * 64 * 8;
    constexpr int TB_STRIDE = 260;
    constexpr int SH_BYTES = (FRAG_SHORTS * 2 > 64 * TB_STRIDE * 2)
                                 ? FRAG_SHORTS * 2 : 64 * TB_STRIDE * 2;
    __shared__ __align__(16) char shraw[SH_BYTES];
    ushort* frag = (ushort*)shraw;
    ushort* tbuf = (ushort*)shraw;

    const int t = threadIdx.x;
    const int row0 = blockIdx.x * 64;
    const float* Ax = (const float*)Av;

    const int w = t >> 6, l = t & 63;

    {
        constexpr int C4 = K / 4;
        constexpr int LC4 = 4;   // K==64
#pragma unroll
        for (int it = 0; it < (64 * C4) / 512; ++it) {
            int jj = it * 512 + t;
            int m = jj & 15;
            int c4 = (jj >> 4) & (C4 - 1);
            int rg = jj >> (4 + LC4);
            int row = row0 + rg * 16 + m;
            ushort4 sv = make_ushort4(0, 0, 0, 0);
            if (row < N) {
                float4 xa = *(const float4*)(Ax + (size_t)row * 8);
                float4 xb = *(const float4*)(Ax + (size_t)row * 8 + 4);
                float xrv[8] = {xa.x, xa.y, xa.z, xa.w, xb.x, xb.y, xb.z, xb.w};
                ushort o[4];
#pragma unroll
                for (int j = 0; j < 4; ++j) {
                    int c = c4 * 4 + j;
                    float a = benc[c];
#pragma unroll
                    for (int u = 0; u < 8; ++u) a = fmaf(xrv[u], Wenc[u * 64 + c], a);
                    o[j] = __half_as_ushort(__float2half(fmaxf(a, 0.f)));
                }
                sv = make_ushort4(o[0], o[1], o[2], o[3]);
            }
            int c = c4 * 4;
            int ks = c >> 5, q = (c >> 3) & 3, jb = c & 7;
            int cell = (ks * 4 + rg) * 64 + m + 16 * q;
            *(ushort4*)(frag + cell * 8 + jb) = sv;
        }
    }
    __syncthreads();

    const int ct0 = w * 4;

    f32x4 acc[4][4];
#pragma unroll
    for (int rt = 0; rt < 4; ++rt)
#pragma unroll
        for (int c = 0; c < 4; ++c) acc[rt][c] = (f32x4){0.f, 0.f, 0.f, 0.f};

#pragma unroll
    for (int ks = 0; ks < KS; ++ks) {
        half8 a[4];
#pragma unroll
        for (int rt = 0; rt < 4; ++rt) {
            int cell = (ks * 4 + rt) * 64 + l;
            a[rt] = *(const half8*)(frag + cell * 8);
        }
#pragma unroll
        for (int c = 0; c < 4; ++c) {
            size_t e = ((size_t)(ks * 32 + ct0 + c) * 64 + l) * 8;
            half8 bh = *(const half8*)(Bfrag + e);
#pragma unroll
            for (int rt = 0; rt < 4; ++rt)
                acc[rt][c] = __builtin_amdgcn_mfma_f32_16x16x32_f16(a[rt], bh, acc[rt][c], 0, 0, 0);
        }
    }

    const int m = l & 15, q = l >> 4;
#pragma unroll
    for (int half = 0; half < 2; ++half) {
        __syncthreads();
        if ((w >> 2) == half) {
            const float* bias = half ? br : bl;
#pragma unroll
            for (int c = 0; c < 4; ++c) {
                int col = ((ct0 + c) & 15) * 16 + m;
                float bb = bias[col];
#pragma unroll
                for (int rt = 0; rt < 4; ++rt)
#pragma unroll
                    for (int r = 0; r < 4; ++r)
                        tbuf[(rt * 16 + q * 4 + r) * TB_STRIDE + col] =
                            __half_as_ushort(__float2half(acc[rt][c][r] + bb));
            }
        }
        __syncthreads();
        ushort* outp = half ? outR : outL;
#pragma unroll
        for (int it = 0; it < 4; ++it) {
            int jj = it * 512 + t;
            int row = jj >> 5;
            int ch = jj & 31;
            int grow = row0 + row;
            if (grow < N) {
                uint2 a0 = *(const uint2*)(tbuf + row * TB_STRIDE + ch * 8);
                uint2 a1 = *(const uint2*)(tbuf + row * TB_STRIDE + ch * 8 + 4);
                *(uint4*)(outp + (size_t)grow * 256 + ch * 8) =
                    make_uint4(a0.x, a0.y, a1.x, a1.y);
            }
        }
    }
}

// ---------------------------------------------------------------------------
// K=256 GEMM (R28): M=32 tile, 4 waves (256 thr), 4 blocks/CU at the
// 128-reg cap. DMA staging (4 issues/thread, wave-uniform LDS dest) ->
// LDS ds_read K-loop (acc[2][8], 2 A + 4 B frags live) -> single-pass
// all-wave 32x516 tbuf -> uint4 full-line row stores. 3 barriers.
// outR may alias A (block touches only its own 32 rows).
// ---------------------------------------------------------------------------
__global__ __launch_bounds__(256, 4) void gemm_mfma32(
    const ushort* __restrict__ A, const ushort* __restrict__ Bfrag,
    const float* __restrict__ bl, const float* __restrict__ br,
    ushort* __restrict__ outL, ushort* outR, int N) {
    constexpr int TB_STRIDE = 516;
    constexpr int SH_BYTES = 32 * TB_STRIDE * 2;   // 33024 > 16KB frag
    __shared__ __align__(16) char shraw[SH_BYTES];
    ushort* frag = (ushort*)shraw;
    ushort* tbuf = (ushort*)shraw;

    const int t = threadIdx.x;
    const int row0 = blockIdx.x * 32;
    const int w = t >> 6, l = t & 63;

    // stage A-tile (32 rows x 256 ch): cell_blk cb = ks*2+rg, cb = w*4+it
#if __has_builtin(__builtin_amdgcn_global_load_lds)
#pragma unroll
    for (int it = 0; it < 4; ++it) {
        int cb = w * 4 + it;              // 0..15
        int ks = cb >> 1, rg = cb & 1;
        int row = row0 + rg * 16 + (l & 15);
        const ushort* srcp = A + (size_t)row * 256 + ks * 32 + (l >> 4) * 8;
        ushort* dstp = frag + (size_t)cb * 512;   // wave-uniform base
        if (row < N) {
            __builtin_amdgcn_global_load_lds(
                (const __attribute__((address_space(1))) unsigned int*)srcp,
                (__attribute__((address_space(3))) unsigned int*)dstp,
                16, 0, 0);
        }
    }
#else
#pragma unroll
    for (int it = 0; it < 4; ++it) {
        int cb = w * 4 + it;
        int ks = cb >> 1, rg = cb & 1;
        int row = row0 + rg * 16 + (l & 15);
        uint4 sv = make_uint4(0, 0, 0, 0);
        if (row < N) sv = *(const uint4*)(A + (size_t)row * 256 + ks * 32 + (l >> 4) * 8);
        *(uint4*)(frag + (size_t)cb * 512 + l * 8) = sv;
    }
#endif
    __syncthreads();

    f32x4 acc[2][8];
#pragma unroll
    for (int rt = 0; rt < 2; ++rt)
#pragma unroll
        for (int c = 0; c < 8; ++c) acc[rt][c] = (f32x4){0.f, 0.f, 0.f, 0.f};

#pragma unroll
    for (int ks = 0; ks < 8; ++ks) {
        half8 a0 = *(const half8*)(frag + ((ks * 2 + 0) * 64 + l) * 8);
        half8 a1 = *(const half8*)(frag + ((ks * 2 + 1) * 64 + l) * 8);
#pragma unroll
        for (int ch_ = 0; ch_ < 2; ++ch_) {     // 2 c-halves: 4 B-frags live
#pragma unroll
            for (int cc = 0; cc < 4; ++cc) {
                int c = ch_ * 4 + cc;
                int ct = w * 8 + c;             // 0..31
                size_t e = ((size_t)(ks * 32 + ct) * 64 + l) * 8;
                half8 bh = *(const half8*)(Bfrag + e);
                acc[0][c] = __builtin_amdgcn_mfma_f32_16x16x32_f16(a0, bh, acc[0][c], 0, 0, 0);
                acc[1][c] = __builtin_amdgcn_mfma_f32_16x16x32_f16(a1, bh, acc[1][c], 0, 0, 0);
            }
        }
    }
    __syncthreads();   // frag reads done; tbuf aliases frag

    const int m = l & 15, q = l >> 4;
#pragma unroll
    for (int c = 0; c < 8; ++c) {
        int ct = w * 8 + c;
        int col = ct * 16 + m;                 // 0..511 (L then R)
        float bb = (ct < 16) ? bl[col] : br[col - 256];
#pragma unroll
        for (int rt = 0; rt < 2; ++rt)
#pragma unroll
            for (int r = 0; r < 4; ++r)
                tbuf[(rt * 16 + q * 4 + r) * TB_STRIDE + col] =
                    __half_as_ushort(__float2half(acc[rt][c][r] + bb));
    }
    __syncthreads();

#pragma unroll
    for (int it = 0; it < 8; ++it) {
        int jj = it * 256 + t;
        int row = jj >> 6;           // 0..31
        int ch = jj & 63;            // 0-31 -> L, 32-63 -> R
        int grow = row0 + row;
        if (grow < N) {
            ushort* outp = (ch < 32) ? outL : outR;
            int cc = (ch & 31) * 8;
            uint2 a0 = *(const uint2*)(tbuf + row * TB_STRIDE + ch * 8);
            uint2 a1 = *(const uint2*)(tbuf + row * TB_STRIDE + ch * 8 + 4);
            *(uint4*)(outp + (size_t)grow * 256 + cc) =
                make_uint4(a0.x, a0.y, a1.x, a1.y);
        }
    }
}

// ---------------------------------------------------------------------------
// GATv2 aggregation (R24b): TWO nodes per wave, natural adjacent pairing.
// Diet: unconditional padded edata loads, cndmask gather addresses,
// att pre-scaled by log2(e) + exp2. NO max-tracking (logits tiny).
// xl/xr/out all FP16; out may ALIAS xr. edata padded >=8 entries.
// ---------------------------------------------------------------------------
__global__ __launch_bounds__(256) void gat_aggregate(
    const ushort* __restrict__ xl, const ushort* xr,
    const int* __restrict__ off, const int2* __restrict__ edata,
    const float* __restrict__ We, const float* __restrict__ att,
    const float* __restrict__ bias, ushort* out, int N) {
    const int wid = blockIdx.x * 4 + (threadIdx.x >> 6);
    if (wid * 2 >= N) return;              // whole-wave uniform exit
    const int lane = threadIdx.x & 63;
    const int l32 = lane & 31;
    const int node = wid * 2 + (lane >> 5);
    const int cbase = (l32 >> 3) * 64 + (l32 & 7) * 8;   // 8 ch per lane
    const unsigned cb2 = (unsigned)cbase * 2;             // byte offset in row

    const float LOG2E = 1.44269504f;
    float4 wf0 = *(const float4*)(We + cbase);
    float4 wf1 = *(const float4*)(We + cbase + 4);
    float4 af0 = *(const float4*)(att + cbase);
    float4 af1 = *(const float4*)(att + cbase + 4);
    h2 we[4], at[4];
    we[0] = pack_h2(wf0.x, wf0.y); we[1] = pack_h2(wf0.z, wf0.w);
    we[2] = pack_h2(wf1.x, wf1.y); we[3] = pack_h2(wf1.z, wf1.w);
    at[0] = pack_h2(af0.x * LOG2E, af0.y * LOG2E);
    at[1] = pack_h2(af0.z * LOG2E, af0.w * LOG2E);
    at[2] = pack_h2(af1.x * LOG2E, af1.y * LOG2E);
    at[3] = pack_h2(af1.z * LOG2E, af1.w * LOG2E);

    const h2 z2 = {(_Float16)0.f, (_Float16)0.f};
    const h2 c02 = {(_Float16)0.2f, (_Float16)0.2f};

    const bool valid = node < N;
    const size_t nb = (size_t)node * HD;
    h2 xrv[4] = {z2, z2, z2, z2};
    int s0i = 0, s1i = 0;
    if (valid) {
        uint4 xu = *(const uint4*)(xr + nb + cbase);
        xrv[0] = __builtin_bit_cast(h2, xu.x);
        xrv[1] = __builtin_bit_cast(h2, xu.y);
        xrv[2] = __builtin_bit_cast(h2, xu.z);
        xrv[3] = __builtin_bit_cast(h2, xu.w);
        s0i = off[node];
        s1i = off[node + 1];
    }

    const char* xlb = (const char*)xl;
    const char* eb = (const char*)edata;
    float l = 0.f;
    h2 acc[4] = {z2, z2, z2, z2};

    // unconditional prologue prefetch (edata padded by 8 entries)
    int j[4];
    float ea[4];
    {
        unsigned tb = (unsigned)s0i << 3;
        int2 e0 = *(const int2*)(eb + tb);
        int2 e1 = *(const int2*)(eb + tb + 8);
        int2 e2 = *(const int2*)(eb + tb + 16);
        int2 e3 = *(const int2*)(eb + tb + 24);
        j[0] = e0.x; ea[0] = __int_as_float(e0.y);
        j[1] = e1.x; ea[1] = __int_as_float(e1.y);
        j[2] = e2.x; ea[2] = __int_as_float(e2.y);
        j[3] = e3.x; ea[3] = __int_as_float(e3.y);
    }
    int t = s0i;
    while (__any(t < s1i)) {
        int nE = s1i - t;                 // uniform within each half; may be <=0
        int jc[4];
        float eac[4];
#pragma unroll
        for (int u = 0; u < 4; ++u) { jc[u] = j[u]; eac[u] = ea[u]; }
        // gathers: cndmask address (masked slots -> row 0, stays L1-hot)
        h2 xv[4][4];
#pragma unroll
        for (int u = 0; u < 4; ++u) {
            unsigned a = (u < nE) ? (unsigned)jc[u] : 0u;
            uint4 xu = *(const uint4*)(xlb + (a + cb2));
            xv[u][0] = __builtin_bit_cast(h2, xu.x);
            xv[u][1] = __builtin_bit_cast(h2, xu.y);
            xv[u][2] = __builtin_bit_cast(h2, xu.z);
            xv[u][3] = __builtin_bit_cast(h2, xu.w);
        }
        // unconditional next-batch prefetch (padded)
        {
            unsigned tb = (unsigned)(t + 4) << 3;
            int2 e0 = *(const int2*)(eb + tb);
            int2 e1 = *(const int2*)(eb + tb + 8);
            int2 e2 = *(const int2*)(eb + tb + 16);
            int2 e3 = *(const int2*)(eb + tb + 24);
            j[0] = e0.x; ea[0] = __int_as_float(e0.y);
            j[1] = e1.x; ea[1] = __int_as_float(e1.y);
            j[2] = e2.x; ea[2] = __int_as_float(e2.y);
            j[3] = e3.x; ea[3] = __int_as_float(e3.y);
        }
        float rr[4];
#pragma unroll
        for (int u = 0; u < 4; ++u) {
            _Float16 eh = (_Float16)eac[u];
            h2 e2 = {eh, eh};
            float v = 0.f;
#pragma unroll
            for (int k = 0; k < 4; ++k) {
                h2 s = e2 * we[k] + (xv[u][k] + xrv[k]);
                s = __builtin_elementwise_max(s, z2) + __builtin_elementwise_min(s, z2) * c02;
                v = dot2f(at[k], s, v);
            }
            rr[u] = v;
        }
        // packed butterfly over the 8-lane head group (2 edges per shuffle)
        h2 r01 = pack_h2(rr[0], rr[1]);
        h2 r23 = pack_h2(rr[2], rr[3]);
#pragma unroll
        for (int o = 1; o <= 4; o <<= 1) {
            int v01 = __shfl_xor(__builtin_bit_cast(int, r01), o);
            int v23 = __shfl_xor(__builtin_bit_cast(int, r23), o);
            r01 = r01 + __builtin_bit_cast(h2, v01);
            r23 = r23 + __builtin_bit_cast(h2, v23);
        }
        float r0 = (float)r01.x, r1 = (float)r01.y;
        float r2 = (float)r23.x, r3 = (float)r23.y;
        if (0 >= nE) r0 = -1e30f;
        if (1 >= nE) r1 = -1e30f;
        if (2 >= nE) r2 = -1e30f;
        if (3 >= nE) r3 = -1e30f;
        float p0 = fast_exp2(r0);
        float p1 = fast_exp2(r1);
        float p2 = fast_exp2(r2);
        float p3 = fast_exp2(r3);
        l += (p0 + p1) + (p2 + p3);
        h2 ph0 = pack_h2(p0, p0);
        h2 ph1 = pack_h2(p1, p1);
        h2 ph2 = pack_h2(p2, p2);
        h2 ph3 = pack_h2(p3, p3);
#pragma unroll
        for (int k = 0; k < 4; ++k) {
            acc[k] = ph0 * xv[0][k] + acc[k];
            acc[k] = ph1 * xv[1][k] + acc[k];
            acc[k] = ph2 * xv[2][k] + acc[k];
            acc[k] = ph3 * xv[3][k] + acc[k];
        }
        t += 4;
    }
    if (valid) {
        float inv = 1.f / (l + 1e-16f);
        float4 b0 = *(const float4*)(bias + cbase);
        float4 b1 = *(const float4*)(bias + cbase + 4);
        float q0 = fmaxf(fmaf((float)acc[0].x, inv, b0.x), 0.f);
        float q1 = fmaxf(fmaf((float)acc[0].y, inv, b0.y), 0.f);
        float q2 = fmaxf(fmaf((float)acc[1].x, inv, b0.z), 0.f);
        float q3 = fmaxf(fmaf((float)acc[1].y, inv, b0.w), 0.f);
        float q4 = fmaxf(fmaf((float)acc[2].x, inv, b1.x), 0.f);
        float q5 = fmaxf(fmaf((float)acc[2].y, inv, b1.y), 0.f);
        float q6 = fmaxf(fmaf((float)acc[3].x, inv, b1.z), 0.f);
        float q7 = fmaxf(fmaf((float)acc[3].y, inv, b1.w), 0.f);
        uint w0 = (uint)__half_as_ushort(__float2half(q0)) |
                  ((uint)__half_as_ushort(__float2half(q1)) << 16);
        uint w1 = (uint)__half_as_ushort(__float2half(q2)) |
                  ((uint)__half_as_ushort(__float2half(q3)) << 16);
        uint w2 = (uint)__half_as_ushort(__float2half(q4)) |
                  ((uint)__half_as_ushort(__float2half(q5)) << 16);
        uint w3 = (uint)__half_as_ushort(__float2half(q6)) |
                  ((uint)__half_as_ushort(__float2half(q7)) << 16);
        *(uint4*)(out + nb + cbase) = make_uint4(w0, w1, w2, w3);
    }
}

// ---------------------------------------------------------------------------
__device__ __forceinline__ int lowerb(const int* b, int n, int v) {
    int lo = 0, hi = n;
    while (lo < hi) {
        int mid = (lo + hi) >> 1;
        if (b[mid] < v) lo = mid + 1; else hi = mid;
    }
    return lo;
}

// ---------------------------------------------------------------------------
// pool (R20): 64 graphs x 32 parts = 2048 blocks (full occupancy). Lane owns
// 8 channels (uint4 load = 16B; wave covers 2 contiguous rows/iter). 8 row
// slots accumulate fp32 in regs; slot-pair reduce via shfl_xor(32), cross-
// wave reduce via padded LDS; one fp32 atomicAdd per thread (256/block).
// ---------------------------------------------------------------------------
__global__ __launch_bounds__(256) void pool_kernel(
    const ushort* __restrict__ h, const int* __restrict__ batch,
    float* __restrict__ pooled, float* __restrict__ gcnt, int N) {
    const int g = blockIdx.x >> 5, part = blockIdx.x & 31;
    const int start = lowerb(batch, N, g);
    const int end = lowerb(batch, N, g + 1);
    const int rows = end - start;
    const int r0 = start + (int)((long long)rows * part / 32);
    const int r1 = start + (int)((long long)rows * (part + 1) / 32);

    const int slot = threadIdx.x >> 5;      // 0..7 row slots
    const int l32 = threadIdx.x & 31;       // channel group: 8 ch per lane

    float acc[8] = {0.f, 0.f, 0.f, 0.f, 0.f, 0.f, 0.f, 0.f};
    for (int r = r0 + slot; r < r1; r += 8) {
        uint4 v = *(const uint4*)(h + (size_t)r * HD + l32 * 8);
        h2 a0 = __builtin_bit_cast(h2, v.x);
        h2 a1 = __builtin_bit_cast(h2, v.y);
        h2 a2 = __builtin_bit_cast(h2, v.z);
        h2 a3 = __builtin_bit_cast(h2, v.w);
        acc[0] += (float)a0.x; acc[1] += (float)a0.y;
        acc[2] += (float)a1.x; acc[3] += (float)a1.y;
        acc[4] += (float)a2.x; acc[5] += (float)a2.y;
        acc[6] += (float)a3.x; acc[7] += (float)a3.y;
    }
    // combine slot pairs within each wave (lane ^ 32 has the partner slot)
#pragma unroll
    for (int k = 0; k < 8; ++k) acc[k] += __shfl_xor(acc[k], 32);

    __shared__ float sred[4][32][9];        // pad 9: conflict-free
    const int w = threadIdx.x >> 6;
    if ((threadIdx.x & 63) < 32) {
#pragma unroll
        for (int k = 0; k < 8; ++k) sred[w][l32][k] = acc[k];
    }
    __syncthreads();
    {
        const int li = threadIdx.x >> 3;    // 0..31 channel group
        const int k = threadIdx.x & 7;      // 0..7 within group
        float s = (sred[0][li][k] + sred[1][li][k]) +
                  (sred[2][li][k] + sred[3][li][k]);
        atomicAdd(&pooled[g * HD + li * 8 + k], s);
    }
    if (part == 0 && threadIdx.x == 0) gcnt[g] = (float)rows;
}

// ---------------------------------------------------------------------------
__global__ void mlp_kernel(const float* __restrict__ pooled, const float* __restrict__ gcnt,
                           const float* __restrict__ W_p1, const float* __restrict__ b_p1,
                           const float* __restrict__ ln_g, const float* __restrict__ ln_b,
                           const float* __restrict__ W_p2, const float* __restrict__ b_p2,
                           const float* __restrict__ W_head, const float* __restrict__ b_head,
                           float* __restrict__ out) {
    int g = blockIdx.x;
    int j = threadIdx.x;
    __shared__ float sh[128];
    __shared__ float red[2];

    float inv = 1.f / fmaxf(gcnt[g], 1.f);
    float v = b_p1[j];
    for (int k = 0; k < 256; ++k) v = fmaf(pooled[g * 256 + k] * inv, W_p1[k * 128 + j], v);

    float s = v;
    for (int o = 32; o > 0; o >>= 1) s += __shfl_xor(s, o);
    if ((j & 63) == 0) red[j >> 6] = s;
    __syncthreads();
    float mu = (red[0] + red[1]) * (1.f / 128.f);
    float d = v - mu;
    float s2 = d * d;
    for (int o = 32; o > 0; o >>= 1) s2 += __shfl_xor(s2, o);
    __syncthreads();
    if ((j & 63) == 0) red[j >> 6] = s2;
    __syncthreads();
    float var = (red[0] + red[1]) * (1.f / 128.f);

    float p = d * rsqrtf(var + 1e-5f) * ln_g[j] + ln_b[j];
    sh[j] = fmaxf(p, 0.f);
    __syncthreads();

    if (j < 64) {
        float q = b_p2[j];
        for (int k = 0; k < 128; ++k) q = fmaf(sh[k], W_p2[k * 64 + j], q);
        q = fmaxf(q, 0.f);
        float t = q * W_head[j];
        for (int o = 32; o > 0; o >>= 1) t += __shfl_xor(t, o);
        if (j == 0) out[g] = t + b_head[0];
    }
}

// ---------------------------------------------------------------------------
extern "C" void kernel_launch(void* const* d_in, const int* in_sizes, int n_in,
                              void* d_out, int out_size, void* d_ws, size_t ws_size,
                              hipStream_t stream) {
    const float* x      = (const float*)d_in[0];
    const float* eattr  = (const float*)d_in[1];
    const int*   src    = (const int*)d_in[2];
    const int*   dst    = (const int*)d_in[3];
    const int*   batch  = (const int*)d_in[4];
    const float* W_enc  = (const float*)d_in[5];
    const float* b_enc  = (const float*)d_in[6];
    const float* g1_Wl  = (const float*)d_in[7];
    const float* g1_bl  = (const float*)d_in[8];
    const float* g1_Wr  = (const float*)d_in[9];
    const float* g1_br  = (const float*)d_in[10];
    const float* g1_We  = (const float*)d_in[11];
    const float* g1_att = (const float*)d_in[12];
    const float* g1_bias= (const float*)d_in[13];
    const float* g2_Wl  = (const float*)d_in[14];
    const float* g2_bl  = (const float*)d_in[15];
    const float* g2_Wr  = (const float*)d_in[16];
    const float* g2_br  = (const float*)d_in[17];
    const float* g2_We  = (const float*)d_in[18];
    const float* g2_att = (const float*)d_in[19];
    const float* g2_bias= (const float*)d_in[20];
    const float* W_p1   = (const float*)d_in[21];
    const float* b_p1   = (const float*)d_in[22];
    const float* ln_g   = (const float*)d_in[23];
    const float* ln_b   = (const float*)d_in[24];
    const float* W_p2   = (const float*)d_in[25];
    const float* b_p2   = (const float*)d_in[26];
    const float* W_head = (const float*)d_in[27];
    const float* b_head = (const float*)d_in[28];

    const int N = in_sizes[0] / 8;   // 100000
    const int E = in_sizes[2];       // 400000

    // workspace layout (~114 MB)
    char* p = (char*)d_ws;
    auto alloc = [&](size_t bytes) -> void* {
        void* r = (void*)p;
        p += (bytes + 255) & ~(size_t)255;
        return r;
    };
    ushort* bufA   = (ushort*)alloc((size_t)N * HD * 2);  // XR / h fp16 (in-place)
    ushort* bufXL  = (ushort*)alloc((size_t)N * HD * 2);  // XL fp16 (gather target)
    // contiguous zero region: cnt, cur, pooled
    int*    cnt    = (int*)alloc((size_t)N * 4);
    int*    curp   = (int*)alloc((size_t)N * 4);
    float*  pooled = (float*)alloc(64 * HD * 4);
    char*   zend   = p;
    int*    off    = (int*)alloc((size_t)(N + 1) * 4);
    int2*   edata  = (int2*)alloc((size_t)(E + 8) * 8);   // (src*512, eattr); +8 pad
    const int nb   = (N + 255) / 256;
    int*    bsum   = (int*)alloc((size_t)nb * 4);
    float*  gcnt   = (float*)alloc(64 * 4);
    ushort* wfrag1 = (ushort*)alloc((size_t)64 * 64 * 16 * 2);   // K=64, single region
    ushort* wfrag2 = (ushort*)alloc((size_t)256 * 64 * 16 * 2);  // K=256, single region

    const int nzero = (int)(((char*)zend - (char*)cnt) / 4);
    const int nsetup = nzero + 64 * 64 + 256 * 64;

    // ---- setup: zero cnt/cur/pooled + build both fp16 B-frag files ----
    setup_kernel<<<(nsetup + 255) / 256, 256, 0, stream>>>(
        cnt, nzero, g1_Wl, g1_Wr, wfrag1, g2_Wl, g2_Wr, wfrag2);

    // ---- CSR by dst ----
    deg_kernel<<<(E + 255) / 256, 256, 0, stream>>>(dst, cnt, E);
    scan_block<<<nb, 256, 0, stream>>>(cnt, off, bsum, N);
    scan_add2<<<nb, 256, 0, stream>>>(off, bsum, N);
    scatter_kernel<<<(E + 255) / 256, 256, 0, stream>>>(dst, src, eattr, off, curp,
                                                        edata, E);

    const int gblocks = (N + 63) / 64;
    const int g32blocks = (N + 31) / 32;
    const int ablocks = (N + 7) / 8;   // 2 nodes/wave, 4 waves/block

    // ---- GAT layer 1 (encoder fused into staging): x -> XL(fp16), XR(fp16)
    gemm_mfma<64, true><<<gblocks, 512, 0, stream>>>(
        x, W_enc, b_enc, wfrag1, g1_bl, g1_br, bufXL, bufA, N);
    gat_aggregate<<<ablocks, 256, 0, stream>>>(
        bufXL, bufA, off, edata, g1_We, g1_att, g1_bias, bufA, N);

    // ---- GAT layer 2: h1(fp16) -> XL(fp16), XR in-place(fp16); aggregate
    gemm_mfma32<<<g32blocks, 256, 0, stream>>>(
        bufA, wfrag2, g2_bl, g2_br, bufXL, bufA, N);
    gat_aggregate<<<ablocks, 256, 0, stream>>>(
        bufXL, bufA, off, edata, g2_We, g2_att, g2_bias, bufA, N);

    // ---- pool + MLP head ----
    pool_kernel<<<64 * 32, 256, 0, stream>>>(bufA, batch, pooled, gcnt, N);
    mlp_kernel<<<64, 128, 0, stream>>>(pooled, gcnt, W_p1, b_p1, ln_g, ln_b,
                                       W_p2, b_p2, W_head, b_head, (float*)d_out);
}

// Round 12
// 354.563 us; speedup vs baseline: 1.1171x; 1.1171x over previous
//
#include <hip/hip_runtime.h>
#include <hip/hip_fp16.h>
#include <math.h>

// Problem constants: N=100000, E=400000, G=64, IN=8, H=4, C=64, HD=256.
// R29: FULL REVERT to the proven-best R24b configuration (357.98us).
// Six structural gemm variants regressed (R21 66KB tbuf: -occupancy;
// R22 chunked epilogue: -6us; R25 direct 8B stores: 2x write-amp;
// R26 degree-sort perm: scattered rows; R27 direct A-loads: vmcnt stalls;
// R28 M=32 tile: halved B-reuse). R24b's balance — async global_load_lds
// staging once behind one barrier, LDS-fed MFMA K-loop (short-latency
// ds_read), two-pass tbuf with full-L2-line uint4 row stores, 33KB LDS /
// 128 regs / 2 blocks/CU — is a verified local optimum; all tested
// neighbors are sharply downhill.
// Components: gemm64 w/ fused encoder staging; gemm256 w/ DMA staging;
// gat_aggregate two-nodes-per-wave + instruction diet (padded edata,
// cndmask gathers, exp2 w/ log2e-prescaled att); 2048-block vectorized
// pool; CSR build; 64-block MLP head.

#define HD 256
#define NHEAD 4
#define CH 64

typedef _Float16 half8 __attribute__((ext_vector_type(8)));
typedef _Float16 h2 __attribute__((ext_vector_type(2)));
typedef __attribute__((ext_vector_type(4))) float f32x4;

__device__ __forceinline__ h2 pack_h2(float a, float b) {
#if __has_builtin(__builtin_amdgcn_cvt_pkrtz)
    return __builtin_bit_cast(h2, __builtin_amdgcn_cvt_pkrtz(a, b));
#else
    return h2{(_Float16)a, (_Float16)b};
#endif
}

__device__ __forceinline__ float fast_exp2(float x) {
#if __has_builtin(__builtin_amdgcn_exp2f)
    return __builtin_amdgcn_exp2f(x);
#else
    return exp2f(x);
#endif
}

__device__ __forceinline__ float dot2f(h2 a, h2 b, float c) {
#if __has_builtin(__builtin_amdgcn_fdot2)
    typedef __fp16 fp16v2 __attribute__((ext_vector_type(2)));
    return __builtin_amdgcn_fdot2(__builtin_bit_cast(fp16v2, a),
                                  __builtin_bit_cast(fp16v2, b), c, false);
#else
    return c + (float)a.x * (float)b.x + (float)a.y * (float)b.y;
#endif
}

// ---------------------------------------------------------------------------
// prep_w helper: Wl,Wr [K,256] fp32 -> fp16 B-frag layout (single region).
// Lane holds B[k=(l>>4)*8+j][n=l&15] of tile (ks,ct); ct<16->Wl, else Wr.
// ---------------------------------------------------------------------------
__device__ __forceinline__ void prep_one(const float* Wl, const float* Wr,
                                         ushort* frag, int K, int t) {
    int l = t & 63;
    int ct = (t >> 6) & 31;
    int ks = t >> 11;
    int n = l & 15, q = l >> 4;
    const float* W = (ct < 16) ? Wl : Wr;
    int col = (ct & 15) * 16 + n;
    ushort* phi = frag + (size_t)t * 8;
#pragma unroll
    for (int j = 0; j < 8; ++j) {
        int k = ks * 32 + q * 8 + j;
        float wv = W[(size_t)k * 256 + col];
        phi[j] = __half_as_ushort(__float2half(wv));
    }
}

__global__ void setup_kernel(int* __restrict__ zbase, int nzero,
                             const float* __restrict__ Wl1, const float* __restrict__ Wr1,
                             ushort* __restrict__ f1,
                             const float* __restrict__ Wl2, const float* __restrict__ Wr2,
                             ushort* __restrict__ f2) {
    int i = blockIdx.x * 256 + threadIdx.x;
    if (i < nzero) {
        zbase[i] = 0;
    } else {
        int gt = i - nzero;
        if (gt < 64 * 64) prep_one(Wl1, Wr1, f1, 64, gt);
        else if (gt < 64 * 64 + 256 * 64) prep_one(Wl2, Wr2, f2, 256, gt - 64 * 64);
    }
}

// ---------------------------------------------------------------------------
// CSR build: degree histogram -> scan (2 kernels) -> scatter (packed int2).
// ---------------------------------------------------------------------------
__global__ void deg_kernel(const int* __restrict__ dst, int* __restrict__ cnt, int E) {
    int e = blockIdx.x * 256 + threadIdx.x;
    if (e < E) atomicAdd(&cnt[dst[e]], 1);
}

__global__ void scan_block(const int* __restrict__ cnt, int* __restrict__ off,
                           int* __restrict__ bsum, int N) {
    __shared__ int s[256];
    int i = blockIdx.x * 256 + threadIdx.x;
    int v = (i < N) ? cnt[i] : 0;
    s[threadIdx.x] = v;
    __syncthreads();
    for (int d = 1; d < 256; d <<= 1) {
        int t = 0;
        if (threadIdx.x >= d) t = s[threadIdx.x - d];
        __syncthreads();
        s[threadIdx.x] += t;
        __syncthreads();
    }
    if (i < N) off[i + 1] = s[threadIdx.x];
    if (threadIdx.x == 255) bsum[blockIdx.x] = s[255];
    if (blockIdx.x == 0 && threadIdx.x == 0) off[0] = 0;
}

__global__ void scan_add2(int* __restrict__ off, const int* __restrict__ bsum, int N) {
    __shared__ int red[4];
    int b = blockIdx.x;
    int s = 0;
    for (int i = threadIdx.x; i < b; i += 256) s += bsum[i];
    for (int o = 32; o > 0; o >>= 1) s += __shfl_xor(s, o);
    if ((threadIdx.x & 63) == 0) red[threadIdx.x >> 6] = s;
    __syncthreads();
    int prefix = red[0] + red[1] + red[2] + red[3];
    int i = b * 256 + threadIdx.x;
    if (i < N) off[i + 1] += prefix;
}

// edata.x = src*512 (byte offset of row in fp16 [N,256] buffer; fits 31 bits)
__global__ void scatter_kernel(const int* __restrict__ dst, const int* __restrict__ src,
                               const float* __restrict__ eattr, const int* __restrict__ off,
                               int* __restrict__ cur, int2* __restrict__ edata, int E) {
    int e = blockIdx.x * 256 + threadIdx.x;
    if (e < E) {
        int d = dst[e];
        int p = atomicAdd(&cur[d], 1);
        edata[off[d] + p] = make_int2(src[e] << 9, __float_as_int(eattr[e]));
    }
}

// ---------------------------------------------------------------------------
// FP16 MFMA dual GEMM (R24b, proven): 512 thr (8 waves), 64 rows. A fp16
// exact, B fp16 single-term. K=256 staging: async global_load_lds width=16
// (LDS dest = wave-uniform base + lane*16: cell=(w*4+it)*64+l). Epilogue =
// two-pass tbuf 64x260 + uint4 row stores (full-line writes). FUSE_ENC:
// A is x[N,8] fp32, encoder fused in staging. outR may alias A (A fully
// consumed at staging).
// ---------------------------------------------------------------------------
template <int K, bool FUSE_ENC>
__global__ __launch_bounds__(512, 4) void gemm_mfma(
    const void* Av, const float* __restrict__ Wenc, const float* __restrict__ benc,
    const ushort* __restrict__ Bfrag,
    const float* __restrict__ bl, const float* __restrict__ br,
    ushort* __restrict__ outL, ushort* outR, int N) {
    constexpr int KS = K / 32;
    constexpr int FRAG_SHORTS = KS * 4 * 64 * 8;
    constexpr int TB_STRIDE = 260;
    constexpr int SH_BYTES = (FRAG_SHORTS * 2 > 64 * TB_STRIDE * 2)
                                 ? FRAG_SHORTS * 2 : 64 * TB_STRIDE * 2;
    __shared__ __align__(16) char shraw[SH_BYTES];
    ushort* frag = (ushort*)shraw;
    ushort* tbuf = (ushort*)shraw;

    const int t = threadIdx.x;
    const int row0 = blockIdx.x * 64;
    const float* Ax = (const float*)Av;
    const ushort* Ahalf = (const ushort*)Av;

    const int w = t >> 6, l = t & 63;

    if constexpr (FUSE_ENC) {
        constexpr int C4 = K / 4;
        constexpr int LC4 = 4;   // K==64
#pragma unroll
        for (int it = 0; it < (64 * C4) / 512; ++it) {
            int jj = it * 512 + t;
            int m = jj & 15;
            int c4 = (jj >> 4) & (C4 - 1);
            int rg = jj >> (4 + LC4);
            int row = row0 + rg * 16 + m;
            ushort4 sv = make_ushort4(0, 0, 0, 0);
            if (row < N) {
                float4 xa = *(const float4*)(Ax + (size_t)row * 8);
                float4 xb = *(const float4*)(Ax + (size_t)row * 8 + 4);
                float xrv[8] = {xa.x, xa.y, xa.z, xa.w, xb.x, xb.y, xb.z, xb.w};
                ushort o[4];
#pragma unroll
                for (int j = 0; j < 4; ++j) {
                    int c = c4 * 4 + j;
                    float a = benc[c];
#pragma unroll
                    for (int u = 0; u < 8; ++u) a = fmaf(xrv[u], Wenc[u * 64 + c], a);
                    o[j] = __half_as_ushort(__float2half(fmaxf(a, 0.f)));
                }
                sv = make_ushort4(o[0], o[1], o[2], o[3]);
            }
            int c = c4 * 4;
            int ks = c >> 5, q = (c >> 3) & 3, jb = c & 7;
            int cell = (ks * 4 + rg) * 64 + m + 16 * q;
            *(ushort4*)(frag + cell * 8 + jb) = sv;
        }
    } else {
        // K=256: async DMA staging. For thread (w,l), iteration it:
        //   LDS cell = (w*4+it)*64 + l  -> byte addr = uniform_base + l*16
        //   global   = row(l&15)*512B + w*64B + (l>>4)*16B (per-lane, OK)
#if __has_builtin(__builtin_amdgcn_global_load_lds)
#pragma unroll
        for (int it = 0; it < 4; ++it) {
            int row = row0 + it * 16 + (l & 15);
            const ushort* srcp = Ahalf + (size_t)row * 256 + w * 32 + (l >> 4) * 8;
            ushort* dstp = frag + (size_t)(w * 4 + it) * 64 * 8;  // wave-uniform
            if (row < N) {
                __builtin_amdgcn_global_load_lds(
                    (const __attribute__((address_space(1))) unsigned int*)srcp,
                    (__attribute__((address_space(3))) unsigned int*)dstp,
                    16, 0, 0);
            }
        }
#else
        constexpr int C8 = K / 8;
        constexpr int LC8 = 5;
#pragma unroll
        for (int it = 0; it < (64 * C8) / 512; ++it) {
            int jj = it * 512 + t;
            int m = jj & 15;
            int c8 = (jj >> 4) & (C8 - 1);
            int rg = jj >> (4 + LC8);
            int row = row0 + rg * 16 + m;
            uint4 sv = make_uint4(0, 0, 0, 0);
            if (row < N) sv = *(const uint4*)(Ahalf + (size_t)row * K + c8 * 8);
            int ks = c8 >> 2, q = c8 & 3;
            int cell = (ks * 4 + rg) * 64 + m + 16 * q;
            *(uint4*)(frag + cell * 8) = sv;
        }
#endif
    }
    __syncthreads();

    const int ct0 = w * 4;

    f32x4 acc[4][4];
#pragma unroll
    for (int rt = 0; rt < 4; ++rt)
#pragma unroll
        for (int c = 0; c < 4; ++c) acc[rt][c] = (f32x4){0.f, 0.f, 0.f, 0.f};

#pragma unroll
    for (int ks = 0; ks < KS; ++ks) {
        half8 a[4];
#pragma unroll
        for (int rt = 0; rt < 4; ++rt) {
            int cell = (ks * 4 + rt) * 64 + l;
            a[rt] = *(const half8*)(frag + cell * 8);
        }
#pragma unroll
        for (int c = 0; c < 4; ++c) {
            size_t e = ((size_t)(ks * 32 + ct0 + c) * 64 + l) * 8;
            half8 bh = *(const half8*)(Bfrag + e);
#pragma unroll
            for (int rt = 0; rt < 4; ++rt)
                acc[rt][c] = __builtin_amdgcn_mfma_f32_16x16x32_f16(a[rt], bh, acc[rt][c], 0, 0, 0);
        }
    }

    const int m = l & 15, q = l >> 4;
#pragma unroll
    for (int half = 0; half < 2; ++half) {
        __syncthreads();
        if ((w >> 2) == half) {
            const float* bias = half ? br : bl;
#pragma unroll
            for (int c = 0; c < 4; ++c) {
                int col = ((ct0 + c) & 15) * 16 + m;
                float bb = bias[col];
#pragma unroll
                for (int rt = 0; rt < 4; ++rt)
#pragma unroll
                    for (int r = 0; r < 4; ++r)
                        tbuf[(rt * 16 + q * 4 + r) * TB_STRIDE + col] =
                            __half_as_ushort(__float2half(acc[rt][c][r] + bb));
            }
        }
        __syncthreads();
        ushort* outp = half ? outR : outL;
#pragma unroll
        for (int it = 0; it < 4; ++it) {
            int jj = it * 512 + t;
            int row = jj >> 5;
            int ch = jj & 31;
            int grow = row0 + row;
            if (grow < N) {
                uint2 a0 = *(const uint2*)(tbuf + row * TB_STRIDE + ch * 8);
                uint2 a1 = *(const uint2*)(tbuf + row * TB_STRIDE + ch * 8 + 4);
                *(uint4*)(outp + (size_t)grow * 256 + ch * 8) =
                    make_uint4(a0.x, a0.y, a1.x, a1.y);
            }
        }
    }
}

// ---------------------------------------------------------------------------
// GATv2 aggregation (R24b): TWO nodes per wave, natural adjacent pairing.
// Diet: unconditional padded edata loads, cndmask gather addresses,
// att pre-scaled by log2(e) + exp2 (v_exp_f32). NO max-tracking (logits
// tiny). Inactive edges/halves masked via r=-1e30 -> p=0. xl/xr/out all
// FP16; out may ALIAS xr. edata MUST be padded by >=8 entries (garbage
// tail never dereferenced: gather addr cndmask'd, logits masked by nE).
// ---------------------------------------------------------------------------
__global__ __launch_bounds__(256) void gat_aggregate(
    const ushort* __restrict__ xl, const ushort* xr,
    const int* __restrict__ off, const int2* __restrict__ edata,
    const float* __restrict__ We, const float* __restrict__ att,
    const float* __restrict__ bias, ushort* out, int N) {
    const int wid = blockIdx.x * 4 + (threadIdx.x >> 6);
    if (wid * 2 >= N) return;              // whole-wave uniform exit
    const int lane = threadIdx.x & 63;
    const int l32 = lane & 31;
    const int node = wid * 2 + (lane >> 5);
    const int cbase = (l32 >> 3) * 64 + (l32 & 7) * 8;   // 8 ch per lane
    const unsigned cb2 = (unsigned)cbase * 2;             // byte offset in row

    const float LOG2E = 1.44269504f;
    float4 wf0 = *(const float4*)(We + cbase);
    float4 wf1 = *(const float4*)(We + cbase + 4);
    float4 af0 = *(const float4*)(att + cbase);
    float4 af1 = *(const float4*)(att + cbase + 4);
    h2 we[4], at[4];
    we[0] = pack_h2(wf0.x, wf0.y); we[1] = pack_h2(wf0.z, wf0.w);
    we[2] = pack_h2(wf1.x, wf1.y); we[3] = pack_h2(wf1.z, wf1.w);
    at[0] = pack_h2(af0.x * LOG2E, af0.y * LOG2E);
    at[1] = pack_h2(af0.z * LOG2E, af0.w * LOG2E);
    at[2] = pack_h2(af1.x * LOG2E, af1.y * LOG2E);
    at[3] = pack_h2(af1.z * LOG2E, af1.w * LOG2E);

    const h2 z2 = {(_Float16)0.f, (_Float16)0.f};
    const h2 c02 = {(_Float16)0.2f, (_Float16)0.2f};

    const bool valid = node < N;
    const size_t nb = (size_t)node * HD;
    h2 xrv[4] = {z2, z2, z2, z2};
    int s0i = 0, s1i = 0;
    if (valid) {
        uint4 xu = *(const uint4*)(xr + nb + cbase);
        xrv[0] = __builtin_bit_cast(h2, xu.x);
        xrv[1] = __builtin_bit_cast(h2, xu.y);
        xrv[2] = __builtin_bit_cast(h2, xu.z);
        xrv[3] = __builtin_bit_cast(h2, xu.w);
        s0i = off[node];
        s1i = off[node + 1];
    }

    const char* xlb = (const char*)xl;
    const char* eb = (const char*)edata;
    float l = 0.f;
    h2 acc[4] = {z2, z2, z2, z2};

    // unconditional prologue prefetch (edata padded by 8 entries)
    int j[4];
    float ea[4];
    {
        unsigned tb = (unsigned)s0i << 3;
        int2 e0 = *(const int2*)(eb + tb);
        int2 e1 = *(const int2*)(eb + tb + 8);
        int2 e2 = *(const int2*)(eb + tb + 16);
        int2 e3 = *(const int2*)(eb + tb + 24);
        j[0] = e0.x; ea[0] = __int_as_float(e0.y);
        j[1] = e1.x; ea[1] = __int_as_float(e1.y);
        j[2] = e2.x; ea[2] = __int_as_float(e2.y);
        j[3] = e3.x; ea[3] = __int_as_float(e3.y);
    }
    int t = s0i;
    while (__any(t < s1i)) {
        int nE = s1i - t;                 // uniform within each half; may be <=0
        int jc[4];
        float eac[4];
#pragma unroll
        for (int u = 0; u < 4; ++u) { jc[u] = j[u]; eac[u] = ea[u]; }
        // gathers: cndmask address (masked slots -> row 0, stays L1-hot)
        h2 xv[4][4];
#pragma unroll
        for (int u = 0; u < 4; ++u) {
            unsigned a = (u < nE) ? (unsigned)jc[u] : 0u;
            uint4 xu = *(const uint4*)(xlb + (a + cb2));
            xv[u][0] = __builtin_bit_cast(h2, xu.x);
            xv[u][1] = __builtin_bit_cast(h2, xu.y);
            xv[u][2] = __builtin_bit_cast(h2, xu.z);
            xv[u][3] = __builtin_bit_cast(h2, xu.w);
        }
        // unconditional next-batch prefetch (padded)
        {
            unsigned tb = (unsigned)(t + 4) << 3;
            int2 e0 = *(const int2*)(eb + tb);
            int2 e1 = *(const int2*)(eb + tb + 8);
            int2 e2 = *(const int2*)(eb + tb + 16);
            int2 e3 = *(const int2*)(eb + tb + 24);
            j[0] = e0.x; ea[0] = __int_as_float(e0.y);
            j[1] = e1.x; ea[1] = __int_as_float(e1.y);
            j[2] = e2.x; ea[2] = __int_as_float(e2.y);
            j[3] = e3.x; ea[3] = __int_as_float(e3.y);
        }
        float rr[4];
#pragma unroll
        for (int u = 0; u < 4; ++u) {
            _Float16 eh = (_Float16)eac[u];
            h2 e2 = {eh, eh};
            float v = 0.f;
#pragma unroll
            for (int k = 0; k < 4; ++k) {
                h2 s = e2 * we[k] + (xv[u][k] + xrv[k]);
                s = __builtin_elementwise_max(s, z2) + __builtin_elementwise_min(s, z2) * c02;
                v = dot2f(at[k], s, v);
            }
            rr[u] = v;
        }
        // packed butterfly over the 8-lane head group (2 edges per shuffle)
        h2 r01 = pack_h2(rr[0], rr[1]);
        h2 r23 = pack_h2(rr[2], rr[3]);
#pragma unroll
        for (int o = 1; o <= 4; o <<= 1) {
            int v01 = __shfl_xor(__builtin_bit_cast(int, r01), o);
            int v23 = __shfl_xor(__builtin_bit_cast(int, r23), o);
            r01 = r01 + __builtin_bit_cast(h2, v01);
            r23 = r23 + __builtin_bit_cast(h2, v23);
        }
        float r0 = (float)r01.x, r1 = (float)r01.y;
        float r2 = (float)r23.x, r3 = (float)r23.y;
        if (0 >= nE) r0 = -1e30f;
        if (1 >= nE) r1 = -1e30f;
        if (2 >= nE) r2 = -1e30f;
        if (3 >= nE) r3 = -1e30f;
        float p0 = fast_exp2(r0);
        float p1 = fast_exp2(r1);
        float p2 = fast_exp2(r2);
        float p3 = fast_exp2(r3);
        l += (p0 + p1) + (p2 + p3);
        h2 ph0 = pack_h2(p0, p0);
        h2 ph1 = pack_h2(p1, p1);
        h2 ph2 = pack_h2(p2, p2);
        h2 ph3 = pack_h2(p3, p3);
#pragma unroll
        for (int k = 0; k < 4; ++k) {
            acc[k] = ph0 * xv[0][k] + acc[k];
            acc[k] = ph1 * xv[1][k] + acc[k];
            acc[k] = ph2 * xv[2][k] + acc[k];
            acc[k] = ph3 * xv[3][k] + acc[k];
        }
        t += 4;
    }
    if (valid) {
        float inv = 1.f / (l + 1e-16f);
        float4 b0 = *(const float4*)(bias + cbase);
        float4 b1 = *(const float4*)(bias + cbase + 4);
        float q0 = fmaxf(fmaf((float)acc[0].x, inv, b0.x), 0.f);
        float q1 = fmaxf(fmaf((float)acc[0].y, inv, b0.y), 0.f);
        float q2 = fmaxf(fmaf((float)acc[1].x, inv, b0.z), 0.f);
        float q3 = fmaxf(fmaf((float)acc[1].y, inv, b0.w), 0.f);
        float q4 = fmaxf(fmaf((float)acc[2].x, inv, b1.x), 0.f);
        float q5 = fmaxf(fmaf((float)acc[2].y, inv, b1.y), 0.f);
        float q6 = fmaxf(fmaf((float)acc[3].x, inv, b1.z), 0.f);
        float q7 = fmaxf(fmaf((float)acc[3].y, inv, b1.w), 0.f);
        uint w0 = (uint)__half_as_ushort(__float2half(q0)) |
                  ((uint)__half_as_ushort(__float2half(q1)) << 16);
        uint w1 = (uint)__half_as_ushort(__float2half(q2)) |
                  ((uint)__half_as_ushort(__float2half(q3)) << 16);
        uint w2 = (uint)__half_as_ushort(__float2half(q4)) |
                  ((uint)__half_as_ushort(__float2half(q5)) << 16);
        uint w3 = (uint)__half_as_ushort(__float2half(q6)) |
                  ((uint)__half_as_ushort(__float2half(q7)) << 16);
        *(uint4*)(out + nb + cbase) = make_uint4(w0, w1, w2, w3);
    }
}

// ---------------------------------------------------------------------------
__device__ __forceinline__ int lowerb(const int* b, int n, int v) {
    int lo = 0, hi = n;
    while (lo < hi) {
        int mid = (lo + hi) >> 1;
        if (b[mid] < v) lo = mid + 1; else hi = mid;
    }
    return lo;
}

// ---------------------------------------------------------------------------
// pool (R20): 64 graphs x 32 parts = 2048 blocks (full occupancy). Lane owns
// 8 channels (uint4 load = 16B; wave covers 2 contiguous rows/iter). 8 row
// slots accumulate fp32 in regs; slot-pair reduce via shfl_xor(32), cross-
// wave reduce via padded LDS; one fp32 atomicAdd per thread (256/block).
// ---------------------------------------------------------------------------
__global__ __launch_bounds__(256) void pool_kernel(
    const ushort* __restrict__ h, const int* __restrict__ batch,
    float* __restrict__ pooled, float* __restrict__ gcnt, int N) {
    const int g = blockIdx.x >> 5, part = blockIdx.x & 31;
    const int start = lowerb(batch, N, g);
    const int end = lowerb(batch, N, g + 1);
    const int rows = end - start;
    const int r0 = start + (int)((long long)rows * part / 32);
    const int r1 = start + (int)((long long)rows * (part + 1) / 32);

    const int slot = threadIdx.x >> 5;      // 0..7 row slots
    const int l32 = threadIdx.x & 31;       // channel group: 8 ch per lane

    float acc[8] = {0.f, 0.f, 0.f, 0.f, 0.f, 0.f, 0.f, 0.f};
    for (int r = r0 + slot; r < r1; r += 8) {
        uint4 v = *(const uint4*)(h + (size_t)r * HD + l32 * 8);
        h2 a0 = __builtin_bit_cast(h2, v.x);
        h2 a1 = __builtin_bit_cast(h2, v.y);
        h2 a2 = __builtin_bit_cast(h2, v.z);
        h2 a3 = __builtin_bit_cast(h2, v.w);
        acc[0] += (float)a0.x; acc[1] += (float)a0.y;
        acc[2] += (float)a1.x; acc[3] += (float)a1.y;
        acc[4] += (float)a2.x; acc[5] += (float)a2.y;
        acc[6] += (float)a3.x; acc[7] += (float)a3.y;
    }
    // combine slot pairs within each wave (lane ^ 32 has the partner slot)
#pragma unroll
    for (int k = 0; k < 8; ++k) acc[k] += __shfl_xor(acc[k], 32);

    __shared__ float sred[4][32][9];        // pad 9: conflict-free
    const int w = threadIdx.x >> 6;
    if ((threadIdx.x & 63) < 32) {
#pragma unroll
        for (int k = 0; k < 8; ++k) sred[w][l32][k] = acc[k];
    }
    __syncthreads();
    {
        const int li = threadIdx.x >> 3;    // 0..31 channel group
        const int k = threadIdx.x & 7;      // 0..7 within group
        float s = (sred[0][li][k] + sred[1][li][k]) +
                  (sred[2][li][k] + sred[3][li][k]);
        atomicAdd(&pooled[g * HD + li * 8 + k], s);
    }
    if (part == 0 && threadIdx.x == 0) gcnt[g] = (float)rows;
}

// ---------------------------------------------------------------------------
__global__ void mlp_kernel(const float* __restrict__ pooled, const float* __restrict__ gcnt,
                           const float* __restrict__ W_p1, const float* __restrict__ b_p1,
                           const float* __restrict__ ln_g, const float* __restrict__ ln_b,
                           const float* __restrict__ W_p2, const float* __restrict__ b_p2,
                           const float* __restrict__ W_head, const float* __restrict__ b_head,
                           float* __restrict__ out) {
    int g = blockIdx.x;
    int j = threadIdx.x;
    __shared__ float sh[128];
    __shared__ float red[2];

    float inv = 1.f / fmaxf(gcnt[g], 1.f);
    float v = b_p1[j];
    for (int k = 0; k < 256; ++k) v = fmaf(pooled[g * 256 + k] * inv, W_p1[k * 128 + j], v);

    float s = v;
    for (int o = 32; o > 0; o >>= 1) s += __shfl_xor(s, o);
    if ((j & 63) == 0) red[j >> 6] = s;
    __syncthreads();
    float mu = (red[0] + red[1]) * (1.f / 128.f);
    float d = v - mu;
    float s2 = d * d;
    for (int o = 32; o > 0; o >>= 1) s2 += __shfl_xor(s2, o);
    __syncthreads();
    if ((j & 63) == 0) red[j >> 6] = s2;
    __syncthreads();
    float var = (red[0] + red[1]) * (1.f / 128.f);

    float p = d * rsqrtf(var + 1e-5f) * ln_g[j] + ln_b[j];
    sh[j] = fmaxf(p, 0.f);
    __syncthreads();

    if (j < 64) {
        float q = b_p2[j];
        for (int k = 0; k < 128; ++k) q = fmaf(sh[k], W_p2[k * 64 + j], q);
        q = fmaxf(q, 0.f);
        float t = q * W_head[j];
        for (int o = 32; o > 0; o >>= 1) t += __shfl_xor(t, o);
        if (j == 0) out[g] = t + b_head[0];
    }
}

// ---------------------------------------------------------------------------
extern "C" void kernel_launch(void* const* d_in, const int* in_sizes, int n_in,
                              void* d_out, int out_size, void* d_ws, size_t ws_size,
                              hipStream_t stream) {
    const float* x      = (const float*)d_in[0];
    const float* eattr  = (const float*)d_in[1];
    const int*   src    = (const int*)d_in[2];
    const int*   dst    = (const int*)d_in[3];
    const int*   batch  = (const int*)d_in[4];
    const float* W_enc  = (const float*)d_in[5];
    const float* b_enc  = (const float*)d_in[6];
    const float* g1_Wl  = (const float*)d_in[7];
    const float* g1_bl  = (const float*)d_in[8];
    const float* g1_Wr  = (const float*)d_in[9];
    const float* g1_br  = (const float*)d_in[10];
    const float* g1_We  = (const float*)d_in[11];
    const float* g1_att = (const float*)d_in[12];
    const float* g1_bias= (const float*)d_in[13];
    const float* g2_Wl  = (const float*)d_in[14];
    const float* g2_bl  = (const float*)d_in[15];
    const float* g2_Wr  = (const float*)d_in[16];
    const float* g2_br  = (const float*)d_in[17];
    const float* g2_We  = (const float*)d_in[18];
    const float* g2_att = (const float*)d_in[19];
    const float* g2_bias= (const float*)d_in[20];
    const float* W_p1   = (const float*)d_in[21];
    const float* b_p1   = (const float*)d_in[22];
    const float* ln_g   = (const float*)d_in[23];
    const float* ln_b   = (const float*)d_in[24];
    const float* W_p2   = (const float*)d_in[25];
    const float* b_p2   = (const float*)d_in[26];
    const float* W_head = (const float*)d_in[27];
    const float* b_head = (const float*)d_in[28];

    const int N = in_sizes[0] / 8;   // 100000
    const int E = in_sizes[2];       // 400000

    // workspace layout (~114 MB)
    char* p = (char*)d_ws;
    auto alloc = [&](size_t bytes) -> void* {
        void* r = (void*)p;
        p += (bytes + 255) & ~(size_t)255;
        return r;
    };
    ushort* bufA   = (ushort*)alloc((size_t)N * HD * 2);  // XR / h fp16 (in-place)
    ushort* bufXL  = (ushort*)alloc((size_t)N * HD * 2);  // XL fp16 (gather target)
    // contiguous zero region: cnt, cur, pooled
    int*    cnt    = (int*)alloc((size_t)N * 4);
    int*    curp   = (int*)alloc((size_t)N * 4);
    float*  pooled = (float*)alloc(64 * HD * 4);
    char*   zend   = p;
    int*    off    = (int*)alloc((size_t)(N + 1) * 4);
    int2*   edata  = (int2*)alloc((size_t)(E + 8) * 8);   // (src*512, eattr); +8 pad
    const int nb   = (N + 255) / 256;
    int*    bsum   = (int*)alloc((size_t)nb * 4);
    float*  gcnt   = (float*)alloc(64 * 4);
    ushort* wfrag1 = (ushort*)alloc((size_t)64 * 64 * 16 * 2);   // K=64, single region
    ushort* wfrag2 = (ushort*)alloc((size_t)256 * 64 * 16 * 2);  // K=256, single region

    const int nzero = (int)(((char*)zend - (char*)cnt) / 4);
    const int nsetup = nzero + 64 * 64 + 256 * 64;

    // ---- setup: zero cnt/cur/pooled + build both fp16 B-frag files ----
    setup_kernel<<<(nsetup + 255) / 256, 256, 0, stream>>>(
        cnt, nzero, g1_Wl, g1_Wr, wfrag1, g2_Wl, g2_Wr, wfrag2);

    // ---- CSR by dst ----
    deg_kernel<<<(E + 255) / 256, 256, 0, stream>>>(dst, cnt, E);
    scan_block<<<nb, 256, 0, stream>>>(cnt, off, bsum, N);
    scan_add2<<<nb, 256, 0, stream>>>(off, bsum, N);
    scatter_kernel<<<(E + 255) / 256, 256, 0, stream>>>(dst, src, eattr, off, curp,
                                                        edata, E);

    const int gblocks = (N + 63) / 64;
    const int ablocks = (N + 7) / 8;   // 2 nodes/wave, 4 waves/block

    // ---- GAT layer 1 (encoder fused into staging): x -> XL(fp16), XR(fp16)
    gemm_mfma<64, true><<<gblocks, 512, 0, stream>>>(
        x, W_enc, b_enc, wfrag1, g1_bl, g1_br, bufXL, bufA, N);
    gat_aggregate<<<ablocks, 256, 0, stream>>>(
        bufXL, bufA, off, edata, g1_We, g1_att, g1_bias, bufA, N);

    // ---- GAT layer 2: h1(fp16) -> XL(fp16), XR in-place(fp16); aggregate
    gemm_mfma<256, false><<<gblocks, 512, 0, stream>>>(
        bufA, nullptr, nullptr, wfrag2, g2_bl, g2_br, bufXL, bufA, N);
    gat_aggregate<<<ablocks, 256, 0, stream>>>(
        bufXL, bufA, off, edata, g2_We, g2_att, g2_bias, bufA, N);

    // ---- pool + MLP head ----
    pool_kernel<<<64 * 32, 256, 0, stream>>>(bufA, batch, pooled, gcnt, N);
    mlp_kernel<<<64, 128, 0, stream>>>(pooled, gcnt, W_p1, b_p1, ln_g, ln_b,
                                       W_p2, b_p2, W_head, b_head, (float*)d_out);
}